// Round 1
// baseline (59.881 us; speedup 1.0000x reference)
//
#include <hip/hip_runtime.h>
#include <math.h>

#define HMAP 1024
#define WMAP 1024
#define NW 16  // waves per block (1024 threads)

__device__ __forceinline__ int clampi(int x, int hi) {
    return x < 0 ? 0 : (x > hi ? hi : x);
}

// Single fused kernel: 1 block x 1024 threads (16 waves). Each 16-lane group
// owns one point; a wave covers 8 points in 2 batches of 4. Radius-5 patch
// (11x11 = 121 px -> 8 clamped loads/lane/group). Chebyshev guard: any pixel
// outside the patch has d2 >= 6^2 = 36, so patch mins <= 36 are certified
// global mins (P(uncertified) ~ 0.7^109 ~ 1e-17/point; exact full-map
// fallback keeps it unconditionally correct). Per-point losses land in LDS;
// wave 0 reproduces the old reduce kernel's exact summation order and writes
// the mean. One dispatch total: removes the second launch + inter-kernel
// serialization that dominated the 58 us floor.
__global__ __launch_bounds__(1024)
void roadloss_fused(const float* __restrict__ hd_map,
                    const int* __restrict__ pred,
                    int n,
                    float* __restrict__ out) {
    __shared__ float lds_loss[1024];

    const int tid  = threadIdx.x;
    const int w    = tid >> 6;   // wave 0..15
    const int lane = tid & 63;
    const int g    = lane >> 4;  // 16-lane group -> one point
    const int t    = lane & 15;

    const int   R     = 5;
    const float GUARD = 36.0f;  // (R+1)^2

    const int nslots = (n + NW - 1) / NW;  // points strided by NW per wave

    for (int sb = 0; sb < nslots; sb += 4) {
        const int  s     = sb + g;
        const int  pt    = w + NW * s;
        const bool valid = (s < nslots) && (pt < n);
        const int  ptc   = valid ? pt : 0;  // safe (real) coords when invalid

        const int2 pp = ((const int2*)pred)[ptc];
        const int  px = pp.x;  // row-center (pred[:,0] vs rows)
        const int  py = pp.y;  // col-center (pred[:,1] vs cols)

        // ---- stage 1: issue all patch loads (clamped => unconditional) ----
        float pv[8];
        float d2v[8];
        bool  inb[8];
#pragma unroll
        for (int ii = 0; ii < 8; ++ii) {
            int i   = t + 16 * ii;      // 0..127 over the 11x11 patch
            int dr  = i / 11 - R;
            int dc  = i % 11 - R;
            int r   = clampi(px + dr, HMAP - 1);
            int c   = clampi(py + dc, WMAP - 1);
            pv[ii]  = hd_map[r * WMAP + c];
            d2v[ii] = (float)(dr * dr + dc * dc);  // exact in fp32
            inb[ii] = (i < 121) &&
                      ((unsigned)(px + dr) < (unsigned)HMAP) &&
                      ((unsigned)(py + dc) < (unsigned)WMAP);
        }

        // ---- 2x2 neighbor check (reference SWAPS coords; JAX clamps) ----
        float nv = 0.0f;
        if (t < 4) {
            int r = clampi(py - 1 + (t >> 1), HMAP - 1);
            int c = clampi(px - 1 + (t & 1), WMAP - 1);
            nv = hd_map[r * WMAP + c];
        }
        const unsigned long long road_mask = __ballot(nv == 1.0f);
        const bool outside_road = ((road_mask >> (g * 16)) & 0xFull) != 0ull;

        // ---- stage 2: split accumulators + 16-lane butterfly min ----
        float on0 = 1e30f, off0 = 1e30f, on1 = 1e30f, off1 = 1e30f;
#pragma unroll
        for (int ii = 0; ii < 8; ++ii) {
            if (inb[ii]) {
                if (ii & 1) {
                    if (pv[ii] != 0.0f) on1  = fminf(on1,  d2v[ii]);
                    else                off1 = fminf(off1, d2v[ii]);
                } else {
                    if (pv[ii] != 0.0f) on0  = fminf(on0,  d2v[ii]);
                    else                off0 = fminf(off0, d2v[ii]);
                }
            }
        }
        float best_on  = fminf(on0, on1);
        float best_off = fminf(off0, off1);
#pragma unroll
        for (int sh = 1; sh < 16; sh <<= 1) {
            best_on  = fminf(best_on,  __shfl_xor(best_on,  sh, 64));
            best_off = fminf(best_off, __shfl_xor(best_off, sh, 64));
        }

        // ---- exact full-map fallback (statistically never taken) ----
        unsigned long long fmask =
            __ballot(valid && (t == 0) &&
                     !(best_on <= GUARD && best_off <= GUARD));
        if (__builtin_expect(fmask != 0ull, 0)) {
            while (fmask) {
                int src = __ffsll((long long)fmask) - 1;
                fmask &= fmask - 1;
                int   fpx = __shfl(px, src, 64);
                int   fpy = __shfl(py, src, 64);
                float bo  = __shfl(best_on,  src, 64);
                float bf  = __shfl(best_off, src, 64);
                for (int i = lane; i < HMAP * WMAP; i += 64) {
                    int r = i >> 10, c = i & (WMAP - 1);
                    int dri = r - fpx, dci = c - fpy;
                    float d2 = (float)(dri * dri + dci * dci);  // < 2^21, exact
                    float m  = hd_map[i];
                    if (m != 0.0f) bo = fminf(bo, d2);
                    else           bf = fminf(bf, d2);
                }
#pragma unroll
                for (int sh = 1; sh < 64; sh <<= 1) {
                    bo = fminf(bo, __shfl_xor(bo, sh, 64));
                    bf = fminf(bf, __shfl_xor(bf, sh, 64));
                }
                if ((lane >> 4) == (src >> 4)) {
                    best_on  = bo;
                    best_off = bf;
                }
            }
        }

        // ---- per-point loss (one lane per group) ----
        if (valid && (t == 0) && pt < 1024) {
            bool outside_frame =
                (px < 0) | (px > HMAP) | (py < 0) | (py > WMAP);
            const float K1  = 21.7f, K2 = 40.0f;
            const float LN2 = 0.6931471805599453f;
            lds_loss[pt] = outside_frame
                ? 0.0f
                : (outside_road ? expf(sqrtf(best_off) * (LN2 / K2))
                                : expf(-best_on / K1));
        }
    }

    __syncthreads();

    // ---- mean: exact replica of the old reduce kernel's arithmetic ----
    if (w == 0) {
        float sum = 0.0f;
        for (int i = lane; i < n; i += 64) sum += lds_loss[i];
#pragma unroll
        for (int d = 1; d < 64; d <<= 1) sum += __shfl_xor(sum, d, 64);
        if (lane == 0) out[0] = sum / (float)n;
    }
}

extern "C" void kernel_launch(void* const* d_in, const int* in_sizes, int n_in,
                              void* d_out, int out_size, void* d_ws,
                              size_t ws_size, hipStream_t stream) {
    const float* hd_map = (const float*)d_in[0];
    const int*   pred   = (const int*)d_in[1];
    float* out = (float*)d_out;
    int n = in_sizes[1] / 2;  // 128

    roadloss_fused<<<1, 1024, 0, stream>>>(hd_map, pred, n, out);
}